// Round 15
// baseline (239.855 us; speedup 1.0000x reference)
//
#include <hip/hip_runtime.h>

typedef unsigned short u16;
typedef unsigned int u32;
typedef __attribute__((ext_vector_type(8))) short bf16x8;
typedef __attribute__((ext_vector_type(4))) float f32x4;

#define B_TOT 16384
#define RPW 16               // batch rows per wave
#define BLK 64               // 1 wave per block
#define NBLK (B_TOT / RPW)   // 1024 blocks
#define TT 30
#define LL 100
#define DTC 0.03f
#define L2E 1.44269504088896f

#define HST 104              // u16 stride of Hs rows (MLP staging only)

// ---- LDS byte offsets (per 1-wave block), total 13568 ----
#define OFF_HS  0            // u16[16][104] = 3328 : hT staging + lv-MLP chain
#define OFF_XS  3328         // u16[16][64]  = 2048 : mean-MLP chain scratch
#define OFF_INP 5376         // u16[16][120] = 3840 : encoder inputs (bf16)
#define OFF_ZB  9216         // u16[16][136] = 4352 : z (K=128 padded); dh f32 alias after
#define SMEM_SZ 13568

// ---- d_ws u16 offsets (unchanged, proven) ----
#define WS_WHHE  0        // [256][72]: cols0-63 whh*scale, 64-67 fold, 68 bias, 69-71 zero
#define WS_WHHD  18432
#define WS_MWS   36864    // mean_Ws 3x[64][64]
#define WS_LWS   49152
#define WS_MWF   61440    // [100][64]
#define WS_LWF   67840
#define WS_WINIT 74240    // [64][128] zero-padded
#define WS_TOTAL 82432

__device__ __forceinline__ float bf2f(u16 u) {
    union { u32 i; float f; } v; v.i = ((u32)u) << 16; return v.f;
}
__device__ __forceinline__ u16 f2bf(float f) {          // RNE
    union { float f; u32 i; } v; v.f = f;
    return (u16)((v.i + 0x7FFFu + ((v.i >> 16) & 1u)) >> 16);
}
__device__ __forceinline__ u16 f2bf_t(float f) {        // truncation (hot paths)
    union { float f; u32 i; } v; v.f = f;
    return (u16)(v.i >> 16);
}
__device__ __forceinline__ u32 pkt(float a, float b) {  // pack 2 bf16 (trunc)
    return (u32)f2bf_t(a) | ((u32)f2bf_t(b) << 16);
}
__device__ __forceinline__ u32 pkr(float a, float b) {  // pack 2 bf16 (RNE)
    return (u32)f2bf(a) | ((u32)f2bf(b) << 16);
}
__device__ __forceinline__ float rcpf(float x) { return __builtin_amdgcn_rcpf(x); }
__device__ __forceinline__ float ex2(float x) { return __builtin_amdgcn_exp2f(x); }
__device__ __forceinline__ float tanh_(float x) {
    x = fminf(fmaxf(x, -15.f), 15.f);
    float e = __expf(2.f * x);
    return (e - 1.f) * rcpf(e + 1.f);
}
__device__ __forceinline__ float leaky(float x) { return x >= 0.f ? x : 0.01f * x; }
__device__ __forceinline__ f32x4 mfma16(bf16x8 a, bf16x8 b, f32x4 c) {
    return __builtin_amdgcn_mfma_f32_16x16x32_bf16(a, b, c, 0, 0, 0);
}

// ================= setup kernel: weight prep into d_ws (unchanged) =================
__global__ void setup_kernel(
    const float* __restrict__ W_se, const float* __restrict__ b_se,
    const float* __restrict__ W_ih_e, const float* __restrict__ W_hh_e,
    const float* __restrict__ b_ih_e, const float* __restrict__ b_hh_e,
    const float* __restrict__ W_ih_d, const float* __restrict__ W_hh_d,
    const float* __restrict__ b_ih_d, const float* __restrict__ b_hh_d,
    const float* __restrict__ mean_Ws, const float* __restrict__ lv_Ws,
    const float* __restrict__ mean_Wf, const float* __restrict__ lv_Wf,
    const float* __restrict__ W_init, u16* __restrict__ ws)
{
    const int gid = blockIdx.x * 256 + threadIdx.x;
    const int nth = gridDim.x * 256;
    for (int i = gid; i < 512; i += nth) {
        int which = i >> 8, row = i & 255, g = row >> 6;
        float s = (g == 2) ? 2.f * L2E : L2E;
        const float* wih = (which ? W_ih_d : W_ih_e) + row * 64;
        float f0=0,f1=0,f2=0,f3=0,fb=0;
        for (int e = 0; e < 64; ++e) {
            float w = wih[e];
            f0 = fmaf(w, W_se[e*4+0], f0);
            f1 = fmaf(w, W_se[e*4+1], f1);
            f2 = fmaf(w, W_se[e*4+2], f2);
            f3 = fmaf(w, W_se[e*4+3], f3);
            fb = fmaf(w, b_se[e], fb);
        }
        fb += (which ? b_ih_d : b_ih_e)[row] + (which ? b_hh_d : b_hh_e)[row];
        u16* dst = ws + (which ? WS_WHHD : WS_WHHE) + row * 72 + 64;
        dst[0]=f2bf(f0*s); dst[1]=f2bf(f1*s); dst[2]=f2bf(f2*s); dst[3]=f2bf(f3*s);
        dst[4]=f2bf(fb*s); dst[5]=0; dst[6]=0; dst[7]=0;
    }
    for (int i = gid; i < 2*16384; i += nth) {
        int which = i >= 16384;
        int j = which ? i - 16384 : i;
        int row = j >> 6, k = j & 63, g = row >> 6;
        float s = (g == 2) ? 2.f * L2E : L2E;
        const float* whh = which ? W_hh_d : W_hh_e;
        ws[(which ? WS_WHHD : WS_WHHE) + row*72 + k] = f2bf(whh[j] * s);
    }
    for (int i = gid; i < 12288; i += nth) {
        ws[WS_MWS + i] = f2bf(mean_Ws[i]);
        ws[WS_LWS + i] = f2bf(lv_Ws[i]);
    }
    for (int i = gid; i < 6400; i += nth) {
        ws[WS_MWF + i] = f2bf(mean_Wf[i]);
        ws[WS_LWF + i] = f2bf(lv_Wf[i]);
    }
    for (int i = gid; i < 8192; i += nth) {
        int r = i >> 7, k = i & 127;
        ws[WS_WINIT + i] = (k < LL) ? f2bf(W_init[r*LL + k]) : (u16)0;
    }
}

// ================= main fused kernel: swapped-layout register LSTM =================
// gates[unit][batch] = W * state : W is the MFMA A-operand (m=unit via lane&15,
// k=(lane>>4)*8+j), state is B (n=batch via lane&15, k same). D: n=batch=lane&15,
// m=unit=(lane>>4)*4+reg -> h stays unit-major in REGISTERS; next-step B rebuilt by
// ds_bpermute (quad relabel at fixed lane&15). No per-step LDS transpose, no
// barriers in the loops. 1 wave owns 16 batch rows; launch_bounds(64,1) -> 512-reg
// budget for AW[4][4][3] (192) + acc (64) + state.
__global__ __launch_bounds__(BLK, 1) void vae_lstm_kernel(
    const float* __restrict__ expert, const float* __restrict__ init_state,
    const float* __restrict__ eps, const u16* __restrict__ ws,
    const float* __restrict__ mean_bs, const float* __restrict__ mean_bf,
    const float* __restrict__ lv_bs, const float* __restrict__ lv_bf,
    const float* __restrict__ b_init, const float* __restrict__ W_c,
    const float* __restrict__ b_c,
    float* __restrict__ out_recons, float* __restrict__ out_expert,
    float* __restrict__ out_mu, float* __restrict__ out_lv)
{
    const int l = threadIdx.x;        // 0..63
    const int lc = l & 15;
    const int quad = l >> 4;
    const int b0 = blockIdx.x * RPW;

    __shared__ __align__(16) char smem[SMEM_SZ];
    u16* Hs  = (u16*)(smem + OFF_HS);
    u16* XS  = (u16*)(smem + OFF_XS);
    u16* inp = (u16*)(smem + OFF_INP);
    u16* zB  = (u16*)(smem + OFF_ZB);
    float* dhS = (float*)(smem + OFF_ZB);   // alias: dh f32 scratch after z consumed

    // ---- staging: out_expert passthrough + rel-xy -> inp ; zero zB ----
    {
        u32* zz = (u32*)zB;
#pragma unroll
        for (int i = 0; i < 17; ++i) zz[l + i * 64] = 0;       // 4352 B
        const int base = b0 * (TT*4);
#pragma unroll 4
        for (int i = 0; i < 30; ++i) {
            int idx = l + i * 64;            // 0..1919
            int row = idx / 120, q = idx % 120;
            int t = q >> 2, k = q & 3;
            float v = expert[base + idx];
            out_expert[base + idx] = v;
            float r = v;
            if (k < 2 && t > 0) r = v - expert[base + idx - 4];
            inp[row*120 + q] = f2bf(r);
        }
        __syncthreads();
    }

    bf16x8 AW[4][4][3];        // W A-frags: [gate][unit-block][k-block] = 192 regs
    auto loadW = [&](const u16* wsW) {
#pragma unroll
        for (int g = 0; g < 4; ++g)
#pragma unroll
            for (int ub = 0; ub < 4; ++ub)
#pragma unroll
                for (int kb = 0; kb < 3; ++kb)
                    AW[g][ub][kb] = *(const bf16x8*)(wsW + (g*64 + ub*16 + lc)*72
                                                    + kb*32 + quad*8);
        // kb=2, quads 1-3 read past the 72-col row (junk) -- multiplied by B2=0
    };

    u32 P[4][2] = {{0,0},{0,0},{0,0},{0,0}};   // h bf16 packs: [ub][pair]
    float cst[4][4] = {};                      // c-state [ub][r]
    float hval[4][4];                          // h f32 [ub][r]
    const int aLo = ((quad & 1)*32 + lc) * 4;  // bpermute byte-addr: src quad 2*(q&1)
    const int aHi = aLo + 64;                  // src quad 2*(q&1)+1

    auto bsel = [&](u32 plo, u32 phi, int addr) -> u32 {
        int t0 = __builtin_amdgcn_ds_bpermute(addr, (int)plo);
        int t1 = __builtin_amdgcn_ds_bpermute(addr, (int)phi);
        return (u32)(quad < 2 ? t0 : t1);
    };

    union U8 { bf16x8 v; u32 w[4]; };

    // one step: rebuild B from P (prev h), 48 MFMA, epilogue -> new P, cst, hval
    auto lstm_step = [&](u32 b2w0, u32 b2w1) {
        U8 B0, B1, B2;
        B0.w[0] = bsel(P[0][0], P[1][0], aLo);
        B0.w[1] = bsel(P[0][1], P[1][1], aLo);
        B0.w[2] = bsel(P[0][0], P[1][0], aHi);
        B0.w[3] = bsel(P[0][1], P[1][1], aHi);
        B1.w[0] = bsel(P[2][0], P[3][0], aLo);
        B1.w[1] = bsel(P[2][1], P[3][1], aLo);
        B1.w[2] = bsel(P[2][0], P[3][0], aHi);
        B1.w[3] = bsel(P[2][1], P[3][1], aHi);
        B2.w[0] = b2w0; B2.w[1] = b2w1;
        B2.w[2] = (quad == 0) ? 0x00003F80u : 0u;   // bias 1.0 at k=68
        B2.w[3] = 0u;
        f32x4 acc[4][4];
#pragma unroll
        for (int g = 0; g < 4; ++g)
#pragma unroll
            for (int ub = 0; ub < 4; ++ub) {
                f32x4 z = {0.f, 0.f, 0.f, 0.f};
                z = mfma16(AW[g][ub][0], B0.v, z);
                z = mfma16(AW[g][ub][1], B1.v, z);
                acc[g][ub] = mfma16(AW[g][ub][2], B2.v, z);
            }
#pragma unroll
        for (int ub = 0; ub < 4; ++ub) {
#pragma unroll
            for (int r = 0; r < 4; ++r) {
                float Ei = ex2(-acc[0][ub][r]);
                float Ef = ex2(-acc[1][ub][r]);
                float Eg = ex2(-acc[2][ub][r]);
                float Eo = ex2(-acc[3][ub][r]);
                float Pp = (1.f + Ei) * (1.f + Eg);
                float Qq = 1.f + Ef;
                float num = fmaf(cst[ub][r], Pp, (1.f - Eg) * Qq);
                float cc = num * rcpf(Pp * Qq);
                cst[ub][r] = cc;
                float Ec = ex2(-2.f * L2E * cc);
                hval[ub][r] = (1.f - Ec) * rcpf((1.f + Eo) * (1.f + Ec));
            }
            P[ub][0] = pkt(hval[ub][0], hval[ub][1]);
            P[ub][1] = pkt(hval[ub][2], hval[ub][3]);
        }
    };

    // ---- encoder: h in registers, x from inp via quad-0 lanes ----
    loadW(ws + WS_WHHE);
    for (int stp = 0; stp < TT; ++stp) {
        u32 x0 = 0, x1 = 0;
        if (l < 16) {
            const u16* xp = inp + l*120 + stp*4;
            x0 = *(const u32*)xp;
            x1 = *(const u32*)(xp + 2);
        }
        lstm_step(x0, x1);
    }

    // ---- glue: hT (packs) -> Hs batch-major for the MLP section ----
#pragma unroll
    for (int ub = 0; ub < 4; ++ub) {
        *(u32*)(Hs + lc*HST + ub*16 + quad*4)     = P[ub][0];
        *(u32*)(Hs + lc*HST + ub*16 + quad*4 + 2) = P[ub][1];
    }
    __syncthreads();

    // ---- MLPs (R3-verified wave-local code) ----
    auto mlp_hidden = [&](bf16x8 a0, bf16x8 a1, const u16* wsW, const float* bg,
                          u16* outB, int ost) {
#pragma unroll
        for (int u = 0; u < 4; ++u) {
            int n = u*16 + lc;
            const u16* wr = wsW + n*64;
            bf16x8 bb0 = *(const bf16x8*)(wr + quad*8);
            bf16x8 bb1 = *(const bf16x8*)(wr + 32 + quad*8);
            float bv = bg[n];
            f32x4 acc = {bv, bv, bv, bv};
            acc = mfma16(a0, bb0, acc);
            acc = mfma16(a1, bb1, acc);
#pragma unroll
            for (int r = 0; r < 4; ++r)
                outB[(quad*4 + r)*ost + n] = f2bf_t(leaky(acc[r]));
        }
    };

    {
        bf16x8 t0 = *(const bf16x8*)(Hs + lc*HST + quad*8);
        bf16x8 t1 = *(const bf16x8*)(Hs + lc*HST + 32 + quad*8);
        mlp_hidden(t0, t1, ws + WS_MWS, mean_bs, XS, 64);
        mlp_hidden(t0, t1, ws + WS_LWS, lv_bs, Hs, HST);
        bf16x8 m0 = *(const bf16x8*)(XS + lc*64 + quad*8);
        bf16x8 m1 = *(const bf16x8*)(XS + lc*64 + 32 + quad*8);
        mlp_hidden(m0, m1, ws + WS_MWS + 4096, mean_bs + 64, XS, 64);
        bf16x8 v0 = *(const bf16x8*)(Hs + lc*HST + quad*8);
        bf16x8 v1 = *(const bf16x8*)(Hs + lc*HST + 32 + quad*8);
        mlp_hidden(v0, v1, ws + WS_LWS + 4096, lv_bs + 64, Hs, HST);
        m0 = *(const bf16x8*)(XS + lc*64 + quad*8);
        m1 = *(const bf16x8*)(XS + lc*64 + 32 + quad*8);
        mlp_hidden(m0, m1, ws + WS_MWS + 8192, mean_bs + 128, XS, 64);
        v0 = *(const bf16x8*)(Hs + lc*HST + quad*8);
        v1 = *(const bf16x8*)(Hs + lc*HST + 32 + quad*8);
        mlp_hidden(v0, v1, ws + WS_LWS + 8192, lv_bs + 128, Hs, HST);
    }

    float muv[7][4];

    // ---- mean final ----
    {
        bf16x8 fa = *(const bf16x8*)(XS + lc*64 + quad*8);
        bf16x8 fb = *(const bf16x8*)(XS + lc*64 + 32 + quad*8);
#pragma unroll
        for (int nt = 0; nt < 7; ++nt) {
            int n = nt*16 + lc;
            bool ok = (n < LL);
            bf16x8 bb0, bb1;
            if (ok) {
                const u16* wr = ws + WS_MWF + n*64;
                bb0 = *(const bf16x8*)(wr + quad*8);
                bb1 = *(const bf16x8*)(wr + 32 + quad*8);
            } else {
#pragma unroll
                for (int j = 0; j < 8; ++j) { bb0[j] = 0; bb1[j] = 0; }
            }
            float bv = ok ? mean_bf[n] : 0.f;
            f32x4 acc = {bv, bv, bv, bv};
            acc = mfma16(fa, bb0, acc);
            acc = mfma16(fb, bb1, acc);
#pragma unroll
            for (int r = 0; r < 4; ++r) {
                float vv = leaky(acc[r]);
                muv[nt][r] = vv;
                if (ok) out_mu[(size_t)(b0 + quad*4 + r) * LL + n] = vv;
            }
        }
    }

    // ---- logvar final + reparameterization -> zB ----
    {
        bf16x8 fa = *(const bf16x8*)(Hs + lc*HST + quad*8);
        bf16x8 fb = *(const bf16x8*)(Hs + lc*HST + 32 + quad*8);
#pragma unroll
        for (int nt = 0; nt < 7; ++nt) {
            int n = nt*16 + lc;
            bool ok = (n < LL);
            bf16x8 bb0, bb1;
            if (ok) {
                const u16* wr = ws + WS_LWF + n*64;
                bb0 = *(const bf16x8*)(wr + quad*8);
                bb1 = *(const bf16x8*)(wr + 32 + quad*8);
            } else {
#pragma unroll
                for (int j = 0; j < 8; ++j) { bb0[j] = 0; bb1[j] = 0; }
            }
            float bv = ok ? lv_bf[n] : 0.f;
            f32x4 acc = {bv, bv, bv, bv};
            acc = mfma16(fa, bb0, acc);
            acc = mfma16(fb, bb1, acc);
#pragma unroll
            for (int r = 0; r < 4; ++r) {
                if (ok) {
                    float lv = leaky(acc[r]);
                    size_t gi = (size_t)(b0 + quad*4 + r) * LL + n;
                    out_lv[gi] = lv;
                    float zv = tanh_(fmaf(eps[gi], __expf(0.5f * lv), muv[nt][r]));
                    zB[(quad*4 + r)*136 + n] = f2bf_t(zv);
                }
            }
        }
    }

    // ---- dh = z @ W_init^T + b_init (batch-major) -> dhS f32 ----
    {
        bf16x8 az[4];
#pragma unroll
        for (int kt = 0; kt < 4; ++kt)
            az[kt] = *(const bf16x8*)(zB + lc*136 + kt*32 + quad*8);
#pragma unroll
        for (int u = 0; u < 4; ++u) {
            int n = u*16 + lc;
            float bv = b_init[n];
            f32x4 acc = {bv, bv, bv, bv};
#pragma unroll
            for (int kt = 0; kt < 4; ++kt) {
                bf16x8 bi = *(const bf16x8*)(ws + WS_WINIT + n*128 + kt*32 + quad*8);
                acc = mfma16(az[kt], bi, acc);
            }
#pragma unroll
            for (int r = 0; r < 4; ++r)
                dhS[(quad*4 + r)*64 + n] = acc[r];   // overwrites zB (reads done)
        }
    }

    // ---- glue: dh -> unit-major registers (c-state f32 exact, h0 packs) ----
#pragma unroll
    for (int ub = 0; ub < 4; ++ub) {
        f32x4 d4 = *(const f32x4*)(dhS + lc*64 + ub*16 + quad*4);
#pragma unroll
        for (int r = 0; r < 4; ++r) cst[ub][r] = d4[r];
        P[ub][0] = pkt(d4[0], d4[1]);
        P[ub][1] = pkt(d4[2], d4[3]);
    }

    // ---- decoder prep ----
    loadW(ws + WS_WHHD);
    float wcp[4][4], wcs[4][4];
#pragma unroll
    for (int ub = 0; ub < 4; ++ub)
#pragma unroll
        for (int r = 0; r < 4; ++r) {
            int u = ub*16 + quad*4 + r;
            wcp[ub][r] = W_c[u];
            wcs[ub][r] = W_c[64 + u];
        }
    const float bc0 = b_c[0], bc1 = b_c[1];
    float px = 0.f, py = 0.f, ppsi = 0.f, pv = 0.f;
    u32 xw0 = 0, xw1 = 0;
    if (l < 16) {
        const float* is = init_state + (size_t)(b0 + l)*4;
        px = is[0]; py = is[1]; ppsi = is[2]; pv = is[3];
        xw0 = pkr(px, py);
        xw1 = pkr(ppsi, pv);
    }

    // ---- decoder: register LSTM + in-lane ctrl/physics ----
    for (int stp = 0; stp < TT; ++stp) {
        lstm_step(xw0, xw1);
        float p0 = 0.f, p1 = 0.f;
#pragma unroll
        for (int ub = 0; ub < 4; ++ub)
#pragma unroll
            for (int r = 0; r < 4; ++r) {
                p0 = fmaf(hval[ub][r], wcp[ub][r], p0);
                p1 = fmaf(hval[ub][r], wcs[ub][r], p1);
            }
        p0 += __shfl_xor(p0, 16); p1 += __shfl_xor(p1, 16);
        p0 += __shfl_xor(p0, 32); p1 += __shfl_xor(p1, 32);
        if (l < 16) {
            float pedal = p0 + bc0;
            float steer = fminf(fmaxf(p1 + bc1, -0.5f), 0.5f);
            float v1 = fminf(fmaxf(pv + pedal * DTC, 0.f), 30.f);
            float sn, cs;
            __sincosf(ppsi, &sn, &cs);
            float psid = fminf(fmaxf(pv * __tanf(steer) * 0.4f, -1.57f), 1.57f);
            float nx = fmaf(pv * cs, DTC, px);
            float ny = fmaf(pv * sn, DTC, py);
            float npsi = fmaf(psid, DTC, ppsi);
            px = nx; py = ny; ppsi = npsi; pv = v1;
            float4 o; o.x = nx; o.y = ny; o.z = npsi; o.w = v1;
            *(float4*)(out_recons + ((size_t)(b0 + l) * TT + stp) * 4) = o;
            xw0 = pkr(nx, ny);
            xw1 = pkr(npsi, v1);
        }
    }
}

extern "C" void kernel_launch(void* const* d_in, const int* in_sizes, int n_in,
                              void* d_out, int out_size, void* d_ws, size_t ws_size,
                              hipStream_t stream) {
    (void)in_sizes; (void)n_in; (void)ws_size; (void)out_size;
    const float* expert    = (const float*)d_in[0];
    const float* init_st   = (const float*)d_in[1];
    const float* eps       = (const float*)d_in[2];
    const float* W_se      = (const float*)d_in[3];
    const float* b_se      = (const float*)d_in[4];
    const float* W_ih_e    = (const float*)d_in[5];
    const float* W_hh_e    = (const float*)d_in[6];
    const float* b_ih_e    = (const float*)d_in[7];
    const float* b_hh_e    = (const float*)d_in[8];
    const float* mean_Ws   = (const float*)d_in[9];
    const float* mean_bs   = (const float*)d_in[10];
    const float* mean_Wf   = (const float*)d_in[11];
    const float* mean_bf   = (const float*)d_in[12];
    const float* lv_Ws     = (const float*)d_in[13];
    const float* lv_bs     = (const float*)d_in[14];
    const float* lv_Wf     = (const float*)d_in[15];
    const float* lv_bf     = (const float*)d_in[16];
    const float* W_init    = (const float*)d_in[17];
    const float* b_init    = (const float*)d_in[18];
    const float* W_ih_d    = (const float*)d_in[19];
    const float* W_hh_d    = (const float*)d_in[20];
    const float* b_ih_d    = (const float*)d_in[21];
    const float* b_hh_d    = (const float*)d_in[22];
    const float* W_c       = (const float*)d_in[23];
    const float* b_c       = (const float*)d_in[24];

    float* out = (float*)d_out;
    const size_t n_traj = (size_t)B_TOT * TT * 4;
    const size_t n_lat  = (size_t)B_TOT * LL;
    float* out_recons = out;
    float* out_expert = out + n_traj;
    float* out_mu     = out + 2 * n_traj;
    float* out_lv     = out + 2 * n_traj + n_lat;

    u16* ws = (u16*)d_ws;

    setup_kernel<<<64, 256, 0, stream>>>(
        W_se, b_se, W_ih_e, W_hh_e, b_ih_e, b_hh_e,
        W_ih_d, W_hh_d, b_ih_d, b_hh_d,
        mean_Ws, lv_Ws, mean_Wf, lv_Wf, W_init, ws);

    vae_lstm_kernel<<<NBLK, BLK, 0, stream>>>(
        expert, init_st, eps, ws,
        mean_bs, mean_bf, lv_bs, lv_bf, b_init, W_c, b_c,
        out_recons, out_expert, out_mu, out_lv);
}

// Round 16
// 209.160 us; speedup vs baseline: 1.1468x; 1.1468x over previous
//
#include <hip/hip_runtime.h>

typedef unsigned short u16;
typedef unsigned int u32;
typedef __attribute__((ext_vector_type(8))) short bf16x8;
typedef __attribute__((ext_vector_type(4))) float f32x4;

#define B_TOT 16384
#define RR 32
#define BLK 512
#define NBLK (B_TOT / RR)    // 512 blocks, 512 threads -> 2 blocks/CU, 16 waves/CU
#define TT 30
#define LL 100
#define DTC 0.03f
#define L2E 1.44269504088896f

#define HST 104              // u16 stride of H rows (K=96 + pad), 16B aligned
#define HBUF_U16 (RR * HST)  // 3328 u16 per buffer

// ---- LDS byte offsets, total 38912 ----
#define OFF_H   0        // u16 [2][32][104] = 13312
#define OFF_XB  13312    // u16 [2][32][72] = 9216; sRaw f32[3840]=15360B aliases @staging;
                         // sPrev f32[32][4] (+0) / sWc f32[2][64] (+512) alias in decoder
#define OFF_Z   22528    // u16 [32][136] = 8704
#define OFF_U   31232    // 7680: inp bf16[32][30][4] (encoder) -> muB bf16[32][100] (MLP)
#define SMEM_SZ 38912

// ---- d_ws u16 offsets ----
#define WS_WHHE  0        // [256][72]: cols0-63 whh*scale, 64-67 fold, 68 bias, 69-71 zero
#define WS_WHHD  18432
#define WS_MWS   36864    // mean_Ws 3x[64][64]
#define WS_LWS   49152
#define WS_MWF   61440    // [100][64]
#define WS_LWF   67840
#define WS_WINIT 74240    // [64][128] zero-padded
#define WS_TOTAL 82432    // u16 (164864 bytes)

__device__ __forceinline__ float bf2f(u16 u) {
    union { u32 i; float f; } v; v.i = ((u32)u) << 16; return v.f;
}
__device__ __forceinline__ u16 f2bf(float f) {          // RNE (setup / one-shot paths)
    union { float f; u32 i; } v; v.f = f;
    return (u16)((v.i + 0x7FFFu + ((v.i >> 16) & 1u)) >> 16);
}
__device__ __forceinline__ u16 f2bf_t(float f) {        // truncation (hot paths)
    union { float f; u32 i; } v; v.f = f;
    return (u16)(v.i >> 16);
}
__device__ __forceinline__ float rcpf(float x) { return __builtin_amdgcn_rcpf(x); }
__device__ __forceinline__ float ex2(float x) { return __builtin_amdgcn_exp2f(x); }
__device__ __forceinline__ float tanh_(float x) {
    x = fminf(fmaxf(x, -15.f), 15.f);
    float e = __expf(2.f * x);
    return (e - 1.f) * rcpf(e + 1.f);
}
__device__ __forceinline__ float leaky(float x) { return x >= 0.f ? x : 0.01f * x; }
__device__ __forceinline__ f32x4 mfma16(bf16x8 a, bf16x8 b, f32x4 c) {
    return __builtin_amdgcn_mfma_f32_16x16x32_bf16(a, b, c, 0, 0, 0);
}

// ================= setup kernel: weight prep into d_ws =================
__global__ void setup_kernel(
    const float* __restrict__ W_se, const float* __restrict__ b_se,
    const float* __restrict__ W_ih_e, const float* __restrict__ W_hh_e,
    const float* __restrict__ b_ih_e, const float* __restrict__ b_hh_e,
    const float* __restrict__ W_ih_d, const float* __restrict__ W_hh_d,
    const float* __restrict__ b_ih_d, const float* __restrict__ b_hh_d,
    const float* __restrict__ mean_Ws, const float* __restrict__ lv_Ws,
    const float* __restrict__ mean_Wf, const float* __restrict__ lv_Wf,
    const float* __restrict__ W_init, u16* __restrict__ ws)
{
    const int gid = blockIdx.x * 256 + threadIdx.x;
    const int nth = gridDim.x * 256;
    // A: folded input-proj tails (512 dot-tasks)
    for (int i = gid; i < 512; i += nth) {
        int which = i >> 8, row = i & 255, g = row >> 6;
        float s = (g == 2) ? 2.f * L2E : L2E;
        const float* wih = (which ? W_ih_d : W_ih_e) + row * 64;
        float f0=0,f1=0,f2=0,f3=0,fb=0;
        for (int e = 0; e < 64; ++e) {
            float w = wih[e];
            f0 = fmaf(w, W_se[e*4+0], f0);
            f1 = fmaf(w, W_se[e*4+1], f1);
            f2 = fmaf(w, W_se[e*4+2], f2);
            f3 = fmaf(w, W_se[e*4+3], f3);
            fb = fmaf(w, b_se[e], fb);
        }
        fb += (which ? b_ih_d : b_ih_e)[row] + (which ? b_hh_d : b_hh_e)[row];
        u16* dst = ws + (which ? WS_WHHD : WS_WHHE) + row * 72 + 64;
        dst[0]=f2bf(f0*s); dst[1]=f2bf(f1*s); dst[2]=f2bf(f2*s); dst[3]=f2bf(f3*s);
        dst[4]=f2bf(fb*s); dst[5]=0; dst[6]=0; dst[7]=0;
    }
    // B: scaled W_hh rows
    for (int i = gid; i < 2*16384; i += nth) {
        int which = i >= 16384;
        int j = which ? i - 16384 : i;
        int row = j >> 6, k = j & 63, g = row >> 6;
        float s = (g == 2) ? 2.f * L2E : L2E;
        const float* whh = which ? W_hh_d : W_hh_e;
        ws[(which ? WS_WHHD : WS_WHHE) + row*72 + k] = f2bf(whh[j] * s);
    }
    // C: MLP hidden weights
    for (int i = gid; i < 12288; i += nth) {
        ws[WS_MWS + i] = f2bf(mean_Ws[i]);
        ws[WS_LWS + i] = f2bf(lv_Ws[i]);
    }
    // D: MLP final weights
    for (int i = gid; i < 6400; i += nth) {
        ws[WS_MWF + i] = f2bf(mean_Wf[i]);
        ws[WS_LWF + i] = f2bf(lv_Wf[i]);
    }
    // E: W_init zero-padded [64][128]
    for (int i = gid; i < 8192; i += nth) {
        int r = i >> 7, k = i & 127;
        ws[WS_WINIT + i] = (k < LL) ? f2bf(W_init[r*LL + k]) : (u16)0;
    }
}

// ================= main fused kernel =================
// BLK=512: 8 waves; wave w owns M-tile (w>>2) and gate-columns ((w&3)*16 + lcol).
// 2 blocks/CU -> 16 waves/CU (4/SIMD) to fill transcendental-chain stalls.
// launch_bounds(512,4) -> 128-reg budget; kernel needs ~56 -> no spill
// (the (256,8) 64-reg cap spilled in round 5: FETCH 9->252 MB).
__global__ __launch_bounds__(BLK, 4) void vae_lstm_kernel(
    const float* __restrict__ expert, const float* __restrict__ init_state,
    const float* __restrict__ eps, const u16* __restrict__ ws,
    const float* __restrict__ mean_bs, const float* __restrict__ mean_bf,
    const float* __restrict__ lv_bs, const float* __restrict__ lv_bf,
    const float* __restrict__ b_init, const float* __restrict__ W_c,
    const float* __restrict__ b_c,
    float* __restrict__ out_recons, float* __restrict__ out_expert,
    float* __restrict__ out_mu, float* __restrict__ out_lv)
{
    const int tid = threadIdx.x;
    const int b0g = blockIdx.x * RR;
    const int wv = tid >> 6;          // 0..7
    const int Mt = wv >> 2;           // M-tile (batch rows Mt*16..Mt*16+15)
    const int wsub = wv & 3;          // column-group within the gate space
    const int lane = tid & 63;
    const int lcol = lane & 15;
    const int quad = lane >> 4;
    const int jcol = wsub * 16 + lcol;

    __shared__ __align__(16) char smem[SMEM_SZ];
    u16* Hbuf  = (u16*)(smem + OFF_H);
    u16* XB0   = (u16*)(smem + OFF_XB);
    u16* XB1   = XB0 + RR * 72;
    u16* zBuf  = (u16*)(smem + OFF_Z);
    u16* inp   = (u16*)(smem + OFF_U);
    u16* muB   = (u16*)(smem + OFF_U);      // alias: inp dead after encoder
    float* sRaw  = (float*)(smem + OFF_XB); // staging alias
    float* sPrev = (float*)(smem + OFF_XB); // decoder alias (XB dead)
    float* sWc   = (float*)(smem + OFF_XB + 512);

    // ---- staging: load raw (+passthrough), zero H, rel-xy -> inp ----
    {
        const int base = b0g * (TT*4);
        u32* hz = (u32*)Hbuf;
        for (int idx = tid; idx < HBUF_U16; idx += BLK) hz[idx] = 0;   // 13312 B = both buffers
        for (int idx = tid; idx < RR*TT*4; idx += BLK) {
            float v = expert[base + idx];
            sRaw[idx] = v;
            out_expert[base + idx] = v;
        }
        __syncthreads();
        for (int idx = tid; idx < RR*TT*4; idx += BLK) {
            int q = idx % (TT*4);
            int k = q & 3, t = q >> 2;
            int row = idx / (TT*4);
            float v = sRaw[idx];
            if (k < 2 && t > 0) v -= sRaw[idx - 4];
            u16 hv = f2bf(v);
            inp[idx] = hv;
            if (t == 0) Hbuf[row*HST + 64 + k] = hv;
            if (q == 0) {
                Hbuf[row*HST + 68] = 0x3F80;                 // 1.0 (bias column)
                Hbuf[HBUF_U16 + row*HST + 68] = 0x3F80;
            }
        }
        __syncthreads();
    }

    float creg[4] = {0.f, 0.f, 0.f, 0.f};
    bf16x8 bw[4][3];

    auto build_bw = [&](const u16* wsW) {
#pragma unroll
        for (int g = 0; g < 4; ++g) {
            const u16* wr = wsW + (g*64 + jcol) * 72;
            bw[g][0] = *(const bf16x8*)(wr + quad*8);
            bw[g][1] = *(const bf16x8*)(wr + 32 + quad*8);
            if (quad == 0) {
                bw[g][2] = *(const bf16x8*)(wr + 64);
            } else {
                bf16x8 z;
#pragma unroll
                for (int j = 0; j < 8; ++j) z[j] = 0;
                bw[g][2] = z;
            }
        }
    };

    // one LSTM step for this wave's M-tile: MFMA K=96 + fused gate epilogue
    auto lstm_step = [&](const u16* Hc, u16* Hn) {
        const u16* hrow = Hc + (Mt*16 + lcol)*HST;
        bf16x8 a0 = *(const bf16x8*)(hrow + quad*8);
        bf16x8 a1 = *(const bf16x8*)(hrow + 32 + quad*8);
        bf16x8 a2 = *(const bf16x8*)(hrow + 64 + quad*8);
        f32x4 acc[4];
#pragma unroll
        for (int g = 0; g < 4; ++g) {
            f32x4 z = {0.f, 0.f, 0.f, 0.f};
            z = mfma16(a0, bw[g][0], z);
            z = mfma16(a1, bw[g][1], z);
            acc[g] = mfma16(a2, bw[g][2], z);
        }
#pragma unroll
        for (int r = 0; r < 4; ++r) {
            float Ei = ex2(-acc[0][r]);              // exp(-i)
            float Ef = ex2(-acc[1][r]);              // exp(-f)
            float Eg = ex2(-acc[2][r]);              // exp(-2g)
            float Eo = ex2(-acc[3][r]);              // exp(-o)
            float P = (1.f + Ei) * (1.f + Eg);
            float Q = 1.f + Ef;
            // c' = c*sigm(f) + sigm(i)*tanh(g) = [c*P + (1-Eg)*Q] / (P*Q)
            float num = fmaf(creg[r], P, (1.f - Eg) * Q);
            float cc = num * rcpf(P * Q);
            creg[r] = cc;
            float Ec = ex2(-2.f * L2E * cc);         // exp(-2c)
            float h = (1.f - Ec) * rcpf((1.f + Eo) * (1.f + Ec));
            Hn[(Mt*16 + quad*4 + r)*HST + jcol] = f2bf_t(h);
        }
    };

    // ---- encoder ----
    build_bw(ws + WS_WHHE);
    for (int stp = 0; stp < TT; ++stp) {
        const u16* Hc = Hbuf + (stp & 1) * HBUF_U16;
        u16* Hn = Hbuf + ((stp + 1) & 1) * HBUF_U16;
        lstm_step(Hc, Hn);
        if (tid < 128 && stp < TT-1) {
            int row = tid >> 2, k = tid & 3;
            Hn[row*HST + 64 + k] = inp[row*(TT*4) + (stp+1)*4 + k];
        }
        __syncthreads();
    }
    // hT in Hbuf[0] (TT even)

    // zero zBuf (pad cols >= 100 must be 0)
    {
        u32* zb = (u32*)zBuf;
        for (int idx = tid; idx < RR*136/2; idx += BLK) zb[idx] = 0;
    }

    auto mlp_hidden = [&](const u16* inB, int inStride, u16* outB,
                          const u16* wsW, const float* bg) {
        float bv = bg[jcol];
        const u16* wr = wsW + jcol*64;
        bf16x8 bb0 = *(const bf16x8*)(wr + quad*8);
        bf16x8 bb1 = *(const bf16x8*)(wr + 32 + quad*8);
        f32x4 acc = {bv, bv, bv, bv};
        bf16x8 a0 = *(const bf16x8*)(inB + (Mt*16 + lcol)*inStride + quad*8);
        bf16x8 a1 = *(const bf16x8*)(inB + (Mt*16 + lcol)*inStride + 32 + quad*8);
        acc = mfma16(a0, bb0, acc);
        acc = mfma16(a1, bb1, acc);
#pragma unroll
        for (int r = 0; r < 4; ++r)
            outB[(Mt*16 + quad*4 + r)*72 + jcol] = f2bf_t(leaky(acc[r]));
        __syncthreads();
    };

    // 14 tasks (7 n-tiles x 2 M-tiles) over 8 waves: wave w takes t=w and t=w+8
    auto mlp_final = [&](const u16* inB, const u16* wsW, const float* bg, int mode) {
#pragma unroll
        for (int ti = 0; ti < 2; ++ti) {
            int t = wv + ti*8;
            if (t >= 14) continue;
            int nt = t >> 1, Mtl = t & 1;
            int n = nt*16 + lcol;
            bool ok = (n < LL);
            float bv = ok ? bg[n] : 0.f;
            bf16x8 bb0, bb1;
            if (ok) {
                const u16* wr = wsW + n*64;
                bb0 = *(const bf16x8*)(wr + quad*8);
                bb1 = *(const bf16x8*)(wr + 32 + quad*8);
            } else {
#pragma unroll
                for (int j = 0; j < 8; ++j) { bb0[j] = 0; bb1[j] = 0; }
            }
            f32x4 acc = {bv, bv, bv, bv};
            bf16x8 a0 = *(const bf16x8*)(inB + (Mtl*16 + lcol)*72 + quad*8);
            bf16x8 a1 = *(const bf16x8*)(inB + (Mtl*16 + lcol)*72 + 32 + quad*8);
            acc = mfma16(a0, bb0, acc);
            acc = mfma16(a1, bb1, acc);
            if (ok) {
#pragma unroll
                for (int r = 0; r < 4; ++r) {
                    int m = Mtl*16 + quad*4 + r;
                    float vv = leaky(acc[r]);
                    size_t gi = (size_t)(b0g + m) * LL + n;
                    if (mode == 0) {
                        muB[m*LL + n] = f2bf_t(vv);
                        out_mu[gi] = vv;
                    } else {
                        out_lv[gi] = vv;
                        float mu = bf2f(muB[m*LL + n]);
                        float zv = tanh_(fmaf(eps[gi], __expf(0.5f * vv), mu));
                        zBuf[m*136 + n] = f2bf_t(zv);
                    }
                }
            }
        }
        __syncthreads();
    };

    // mean path (hT intact in Hbuf[0])
    mlp_hidden(Hbuf, HST, XB0, ws + WS_MWS, mean_bs);
    mlp_hidden(XB0, 72, XB1, ws + WS_MWS + 4096, mean_bs + 64);
    mlp_hidden(XB1, 72, XB0, ws + WS_MWS + 8192, mean_bs + 128);
    mlp_final(XB0, ws + WS_MWF, mean_bf, 0);
    // logvar path + fused reparameterization
    mlp_hidden(Hbuf, HST, XB0, ws + WS_LWS, lv_bs);
    mlp_hidden(XB0, 72, XB1, ws + WS_LWS + 4096, lv_bs + 64);
    mlp_hidden(XB1, 72, XB0, ws + WS_LWS + 8192, lv_bs + 128);
    mlp_final(XB0, ws + WS_LWF, lv_bf, 1);

    // ---- dh = z @ W_init^T + b_init -> Hbuf[0] + creg; decoder prep ----
    {
        float bv = b_init[jcol];
        const u16* wr = ws + WS_WINIT + jcol*128;
        f32x4 acc = {bv, bv, bv, bv};
#pragma unroll
        for (int kt = 0; kt < 4; ++kt) {
            bf16x8 az = *(const bf16x8*)(zBuf + (Mt*16 + lcol)*136 + kt*32 + quad*8);
            bf16x8 bi = *(const bf16x8*)(wr + kt*32 + quad*8);
            acc = mfma16(az, bi, acc);
        }
#pragma unroll
        for (int r = 0; r < 4; ++r) {
            creg[r] = acc[r];
            Hbuf[(Mt*16 + quad*4 + r)*HST + jcol] = f2bf_t(acc[r]);
        }
        __syncthreads();   // zBuf reads done before sPrev/sWc overwrite XB region
        if (tid < RR*4) {
            float v = init_state[b0g*4 + tid];
            sPrev[tid] = v;
            Hbuf[(tid >> 2)*HST + 64 + (tid & 3)] = f2bf(v);
        }
        if (tid < 128) sWc[tid] = W_c[tid];
        __syncthreads();
    }

    build_bw(ws + WS_WHHD);
    const float bc0 = b_c[0], bc1 = b_c[1];

    // ---- decoder ----
    for (int stp = 0; stp < TT; ++stp) {
        const u16* Hc = Hbuf + (stp & 1) * HBUF_U16;
        u16* Hn = Hbuf + ((stp + 1) & 1) * HBUF_U16;
        lstm_step(Hc, Hn);
        __syncthreads();
        if (tid < 128) {
            int row = tid >> 2, kq = tid & 3;
            const u16* hr = Hn + row*HST + kq*16;
            bf16x8 h0 = *(const bf16x8*)(hr);
            bf16x8 h1 = *(const bf16x8*)(hr + 8);
            const float4* w0 = (const float4*)(sWc + kq*16);
            const float4* w1 = (const float4*)(sWc + 64 + kq*16);
            float a0 = 0.f, a1 = 0.f;
#pragma unroll
            for (int p = 0; p < 2; ++p) {
                float4 wa = w0[2*p], wb = w0[2*p+1];
                float4 va = w1[2*p], vb = w1[2*p+1];
                bf16x8 hh = p ? h1 : h0;
                float hf[8];
#pragma unroll
                for (int j = 0; j < 8; ++j) hf[j] = bf2f((u16)hh[j]);
                a0 = fmaf(hf[0], wa.x, a0); a0 = fmaf(hf[1], wa.y, a0);
                a0 = fmaf(hf[2], wa.z, a0); a0 = fmaf(hf[3], wa.w, a0);
                a0 = fmaf(hf[4], wb.x, a0); a0 = fmaf(hf[5], wb.y, a0);
                a0 = fmaf(hf[6], wb.z, a0); a0 = fmaf(hf[7], wb.w, a0);
                a1 = fmaf(hf[0], va.x, a1); a1 = fmaf(hf[1], va.y, a1);
                a1 = fmaf(hf[2], va.z, a1); a1 = fmaf(hf[3], va.w, a1);
                a1 = fmaf(hf[4], vb.x, a1); a1 = fmaf(hf[5], vb.y, a1);
                a1 = fmaf(hf[6], vb.z, a1); a1 = fmaf(hf[7], vb.w, a1);
            }
            a0 += __shfl_xor(a0, 1); a1 += __shfl_xor(a1, 1);
            a0 += __shfl_xor(a0, 2); a1 += __shfl_xor(a1, 2);
            if (kq == 0) {
                float pedal = a0 + bc0;
                float steer = fminf(fmaxf(a1 + bc1, -0.5f), 0.5f);
                float4 pv = *(const float4*)(sPrev + row*4);
                float x = pv.x, y = pv.y, psi = pv.z, v = pv.w;
                float v1 = fminf(fmaxf(v + pedal * DTC, 0.f), 30.f);
                float sn, cs;
                __sincosf(psi, &sn, &cs);
                float psid = fminf(fmaxf(v * __tanf(steer) * 0.4f, -1.57f), 1.57f);
                float nx = fmaf(v * cs, DTC, x);
                float ny = fmaf(v * sn, DTC, y);
                float npsi = fmaf(psid, DTC, psi);
                float4 o; o.x = nx; o.y = ny; o.z = npsi; o.w = v1;
                *(float4*)(sPrev + row*4) = o;
                *(float4*)(out_recons + ((size_t)(b0g + row) * TT + stp) * 4) = o;
                u32 lo = (u32)f2bf(nx) | ((u32)f2bf(ny) << 16);
                u32 hi = (u32)f2bf(npsi) | ((u32)f2bf(v1) << 16);
                uint2 pk; pk.x = lo; pk.y = hi;
                *(uint2*)(Hn + row*HST + 64) = pk;
            }
        }
        __syncthreads();
    }
}

extern "C" void kernel_launch(void* const* d_in, const int* in_sizes, int n_in,
                              void* d_out, int out_size, void* d_ws, size_t ws_size,
                              hipStream_t stream) {
    (void)in_sizes; (void)n_in; (void)ws_size; (void)out_size;
    const float* expert    = (const float*)d_in[0];
    const float* init_st   = (const float*)d_in[1];
    const float* eps       = (const float*)d_in[2];
    const float* W_se      = (const float*)d_in[3];
    const float* b_se      = (const float*)d_in[4];
    const float* W_ih_e    = (const float*)d_in[5];
    const float* W_hh_e    = (const float*)d_in[6];
    const float* b_ih_e    = (const float*)d_in[7];
    const float* b_hh_e    = (const float*)d_in[8];
    const float* mean_Ws   = (const float*)d_in[9];
    const float* mean_bs   = (const float*)d_in[10];
    const float* mean_Wf   = (const float*)d_in[11];
    const float* mean_bf   = (const float*)d_in[12];
    const float* lv_Ws     = (const float*)d_in[13];
    const float* lv_bs     = (const float*)d_in[14];
    const float* lv_Wf     = (const float*)d_in[15];
    const float* lv_bf     = (const float*)d_in[16];
    const float* W_init    = (const float*)d_in[17];
    const float* b_init    = (const float*)d_in[18];
    const float* W_ih_d    = (const float*)d_in[19];
    const float* W_hh_d    = (const float*)d_in[20];
    const float* b_ih_d    = (const float*)d_in[21];
    const float* b_hh_d    = (const float*)d_in[22];
    const float* W_c       = (const float*)d_in[23];
    const float* b_c       = (const float*)d_in[24];

    float* out = (float*)d_out;
    const size_t n_traj = (size_t)B_TOT * TT * 4;
    const size_t n_lat  = (size_t)B_TOT * LL;
    float* out_recons = out;
    float* out_expert = out + n_traj;
    float* out_mu     = out + 2 * n_traj;
    float* out_lv     = out + 2 * n_traj + n_lat;

    u16* ws = (u16*)d_ws;

    setup_kernel<<<64, 256, 0, stream>>>(
        W_se, b_se, W_ih_e, W_hh_e, b_ih_e, b_hh_e,
        W_ih_d, W_hh_d, b_ih_d, b_hh_d,
        mean_Ws, lv_Ws, mean_Wf, lv_Wf, W_init, ws);

    vae_lstm_kernel<<<NBLK, BLK, 0, stream>>>(
        expert, init_st, eps, ws,
        mean_bs, mean_bf, lv_bs, lv_bf, b_init, W_c, b_c,
        out_recons, out_expert, out_mu, out_lv);
}